// Round 12
// baseline (186.218 us; speedup 1.0000x reference)
//
#include <hip/hip_runtime.h>

typedef unsigned short u16;
typedef __attribute__((ext_vector_type(8))) __bf16 bf16x8;
typedef __attribute__((ext_vector_type(4))) float f32x4;
typedef __attribute__((ext_vector_type(4))) unsigned int u32x4;

#define MFMA16(a, b, c) __builtin_amdgcn_mfma_f32_16x16x32_bf16(a, b, c, 0, 0, 0)

__device__ __forceinline__ u16 f2bf(float f) {
    unsigned u = __float_as_uint(f);
    u = (u + 0x7FFFu + ((u >> 16) & 1u)) >> 16;
    return (u16)u;
}

// async global->LDS, 16B per lane; LDS dest = wave-uniform base + lane*16
__device__ __forceinline__ void gl_lds16(const u16* g, u16* l) {
    __builtin_amdgcn_global_load_lds(
        (const __attribute__((address_space(1))) unsigned int*)g,
        (__attribute__((address_space(3))) unsigned int*)l, 16, 0, 0);
}

static constexpr int Bv = 2, Tv = 2048, Cv = 1024, Hv = 16, Dv = 64;
static constexpr int Mv = Bv * Tv; // 4096

// ws element offsets (u16 elements)
static constexpr size_t OFF_XB = 0;                      // x bf16       [4096,1024]
static constexpr size_t OFF_WQ = 4194304;                // Wq bf16      [1024,1024]
static constexpr size_t OFF_WK = OFF_WQ + 1048576;
static constexpr size_t OFF_WV = OFF_WK + 1048576;
static constexpr size_t OFF_WO = OFF_WV + 1048576;
static constexpr size_t OFF_Q  = OFF_WO + 1048576;       // Q bf16 [M, C]
static constexpr size_t OFF_K  = OFF_Q + 4194304;        // K bf16 [M, C]
static constexpr size_t OFF_VT = OFF_K + 4194304;        // V^T bf16 [C, M]
static constexpr size_t OFF_A  = OFF_VT + 4194304;       // attended bf16 [M, C]

// ---------------- fp32 -> bf16 convert (x + 4 weights) ----------------
__global__ __launch_bounds__(256) void convert_all(
    const float* __restrict__ x,
    const float* __restrict__ wq, const float* __restrict__ wk,
    const float* __restrict__ wv, const float* __restrict__ wo,
    u16* __restrict__ dst)
{
    int i4 = blockIdx.x * blockDim.x + threadIdx.x;
    if (i4 >= 2097152) return;
    int idx = i4 * 4;
    const float* src; int off;
    if (idx < 4194304) { src = x; off = idx; }
    else {
        int rel = idx - 4194304;
        int j = rel >> 20;
        off = rel & 1048575;
        src = (j == 0) ? wq : (j == 1) ? wk : (j == 2) ? wv : wo;
    }
    float4 v = *(const float4*)(src + off);
    ushort4 o;
    o.x = f2bf(v.x); o.y = f2bf(v.y); o.z = f2bf(v.z); o.w = f2bf(v.w);
    *(ushort4*)(dst + idx) = o;
}

// ---------------- 128x128-tile bf16 GEMM, BK=32, packed LDS (qkv) ----------------
// Best-measured qkv structure (R5). 4 waves, 64x64 sub-tiles, packed [64][64]
// LDS, 32 KB double buffer, counted-vmcnt pipeline.
template <bool OUT_BF16, bool ROWBIAS>
__device__ __forceinline__ void gemm128_b32(
    u16* __restrict__ lA0, u16* __restrict__ lB0,
    u16* __restrict__ lA1, u16* __restrict__ lB1,
    const u16* __restrict__ A, const u16* __restrict__ Wt,
    const float* __restrict__ bias, void* __restrict__ outp,
    int m0, int n0, int N, int K)
{
    const int tid  = threadIdx.x;
    const int lane = tid & 63, w = tid >> 6;          // 4 waves
    const int quad = lane >> 4, lm = lane & 15;
    const int wm = (w & 1) * 64, wn = (w >> 1) * 64;  // 2x2 wave grid, 64x64 each
    const int h4A = (w & 1) * 4, h4B = ((w >> 1) & 1) * 4;
    const int rowi = lane >> 3, seg = lane & 7;
    const int raw = seg ^ rowi;
    const int hh  = raw >> 2, qq = raw & 3;

    f32x4 zero = {0.f, 0.f, 0.f, 0.f};
    f32x4 acc[4][4];
    #pragma unroll
    for (int mt = 0; mt < 4; mt++)
        #pragma unroll
        for (int nt = 0; nt < 4; nt++) acc[mt][nt] = zero;

    auto stage = [&](u16* dA, u16* dB, int k0) __attribute__((always_inline)) {
        #pragma unroll
        for (int j = 0; j < 2; j++) {
            int pr0 = w * 16 + j * 8;
            int gr  = pr0 + rowi + (hh << 6);
            gl_lds16(A  + (size_t)(m0 + gr) * K + k0 + qq * 8, &dA[pr0 * 64]);
            gl_lds16(Wt + (size_t)(n0 + gr) * K + k0 + qq * 8, &dB[pr0 * 64]);
        }
    };
    auto compute = [&](const u16* sA, const u16* sB) __attribute__((always_inline)) {
        bf16x8 af[4], bf[4];
        #pragma unroll
        for (int mt = 0; mt < 4; mt++)
            af[mt] = *(const bf16x8*)&sA[(mt * 16 + lm) * 64 + (((h4A + quad) ^ (lm & 7)) * 8)];
        #pragma unroll
        for (int nt = 0; nt < 4; nt++)
            bf[nt] = *(const bf16x8*)&sB[(nt * 16 + lm) * 64 + (((h4B + quad) ^ (lm & 7)) * 8)];
        #pragma unroll
        for (int mt = 0; mt < 4; mt++)
            #pragma unroll
            for (int nt = 0; nt < 4; nt++)
                acc[mt][nt] = MFMA16(af[mt], bf[nt], acc[mt][nt]);
    };

    const int NT = K >> 5;               // 32 steps of BK=32
    stage(lA0, lB0, 0);
    stage(lA1, lB1, 32);
    for (int t = 0; t < NT; ++t) {
        if (t + 1 < NT) asm volatile("s_waitcnt vmcnt(4)" ::: "memory");
        else            asm volatile("s_waitcnt vmcnt(0)" ::: "memory");
        __builtin_amdgcn_s_barrier();
        const u16* sA = (t & 1) ? lA1 : lA0;
        const u16* sB = (t & 1) ? lB1 : lB0;
        compute(sA, sB);
        asm volatile("s_waitcnt lgkmcnt(0)" ::: "memory");
        __builtin_amdgcn_s_barrier();
        if (t + 2 < NT) stage((t & 1) ? lA1 : lA0, (t & 1) ? lB1 : lB0, (t + 2) << 5);
    }

    #pragma unroll
    for (int nt = 0; nt < 4; nt++) {
        int col = n0 + wn + nt * 16 + lm;
        float cb = ROWBIAS ? 0.f : bias[col];
        #pragma unroll
        for (int mt = 0; mt < 4; mt++) {
            #pragma unroll
            for (int r = 0; r < 4; r++) {
                int row = m0 + wm + mt * 16 + quad * 4 + r;
                float v = acc[mt][nt][r] + (ROWBIAS ? bias[row] : cb);
                if (OUT_BF16) ((u16*)outp)[(size_t)row * N + col] = f2bf(v);
                else          ((float*)outp)[(size_t)row * N + col] = v;
            }
        }
    }
}

// fused QKV: 1-D grid of 768 blocks x 256 threads, XCD-swizzled
__global__ __launch_bounds__(256, 3) void gemm_qkv(
    const u16* __restrict__ A,
    const u16* __restrict__ Wq, const u16* __restrict__ Wk, const u16* __restrict__ Wv,
    const float* __restrict__ bq, const float* __restrict__ bk, const float* __restrict__ bv,
    u16* __restrict__ Q, u16* __restrict__ K, u16* __restrict__ VT)
{
    __shared__ u16 lA0[64 * 64];   // packed [64 phys rows][64 cols] = 8 KB each
    __shared__ u16 lB0[64 * 64];
    __shared__ u16 lA1[64 * 64];
    __shared__ u16 lB1[64 * 64];

    int bid = blockIdx.x;
    int sw  = (bid & 7) * 96 + (bid >> 3);
    int g2  = sw >> 5;          // 0..23 = which*8 + col
    int row = sw & 31;          // 0..31 row tile
    int which = g2 >> 3, col = g2 & 7;

    if (which == 0) {
        gemm128_b32<true, false>(lA0, lB0, lA1, lB1, A, Wq, bq, Q, row * 128, col * 128, Cv, Cv);
    } else if (which == 1) {
        gemm128_b32<true, false>(lA0, lB0, lA1, lB1, A, Wk, bk, K, row * 128, col * 128, Cv, Cv);
    } else {
        gemm128_b32<true, true>(lA0, lB0, lA1, lB1, Wv, A, bv, VT, col * 128, row * 128, Mv, Cv);
    }
}

// output proj (R4 version, best measured): 128x64 tiles, BK=64, 512 threads
// (8 waves, 32x32 each), counted-vmcnt dbuf pipeline, 1-D grid 512 blocks.
__global__ __launch_bounds__(512) void gemm_o64(
    const u16* __restrict__ A, const u16* __restrict__ Wt,
    const float* __restrict__ bias, float* __restrict__ outp)
{
    __shared__ u16 lA0[128 * 64];
    __shared__ u16 lA1[128 * 64];
    __shared__ u16 lB0[64 * 64];
    __shared__ u16 lB1[64 * 64];

    const int tid  = threadIdx.x;
    const int lane = tid & 63, w = tid >> 6;          // 0..7
    const int quad = lane >> 4, lm = lane & 15;
    const int wm = (w & 3) * 32, wn = (w >> 2) * 32;  // 4x2 wave grid, 32x32 each

    int bid = blockIdx.x;                  // 512 % 8 == 0
    int sw  = (bid & 7) * 64 + (bid >> 3);
    const int n0 = (sw >> 5) * 64;         // col tile 0..15
    const int m0 = (sw & 31) * 128;        // row tile 0..31
    const int K = Cv;
    const int rowi = lane >> 3, seg = lane & 7;

    f32x4 zero = {0.f, 0.f, 0.f, 0.f};
    f32x4 acc[2][2];
    #pragma unroll
    for (int mt = 0; mt < 2; mt++)
        #pragma unroll
        for (int nt = 0; nt < 2; nt++) acc[mt][nt] = zero;

    auto stage = [&](u16* dA, u16* dB, int k0) __attribute__((always_inline)) {
        #pragma unroll
        for (int i = 0; i < 2; i++) {
            int rbase = w * 16 + i * 8;
            int row = rbase + rowi;
            int gseg = seg ^ (row & 7);
            gl_lds16(A + (size_t)(m0 + row) * K + k0 + gseg * 8, &dA[rbase * 64]);
        }
        {
            int rbase = w * 8, row = rbase + rowi;     // 8 waves x 8 rows = 64
            gl_lds16(Wt + (size_t)(n0 + row) * K + k0 + ((seg ^ (row & 7))) * 8, &dB[rbase * 64]);
        }
    };
    auto compute = [&](const u16* sA, const u16* sB) __attribute__((always_inline)) {
        #pragma unroll
        for (int ks = 0; ks < 2; ks++) {
            const int swz = ((ks * 4 + quad) ^ (lm & 7)) * 8;
            bf16x8 af[2], bf[2];
            #pragma unroll
            for (int mt = 0; mt < 2; mt++)
                af[mt] = *(const bf16x8*)&sA[(wm + mt * 16 + lm) * 64 + swz];
            #pragma unroll
            for (int nt = 0; nt < 2; nt++)
                bf[nt] = *(const bf16x8*)&sB[(wn + nt * 16 + lm) * 64 + swz];
            #pragma unroll
            for (int mt = 0; mt < 2; mt++)
                #pragma unroll
                for (int nt = 0; nt < 2; nt++)
                    acc[mt][nt] = MFMA16(af[mt], bf[nt], acc[mt][nt]);
        }
    };

    const int NT = K >> 6;                 // 16
    stage(lA0, lB0, 0);
    stage(lA1, lB1, 64);
    for (int t = 0; t < NT; ++t) {
        if (t + 1 < NT) asm volatile("s_waitcnt vmcnt(3)" ::: "memory");
        else            asm volatile("s_waitcnt vmcnt(0)" ::: "memory");
        __builtin_amdgcn_s_barrier();
        u16* sA = (t & 1) ? lA1 : lA0;
        u16* sB = (t & 1) ? lB1 : lB0;
        compute(sA, sB);
        asm volatile("s_waitcnt lgkmcnt(0)" ::: "memory");
        __builtin_amdgcn_s_barrier();
        if (t + 2 < NT) stage(sA, sB, (t + 2) << 6);
    }

    #pragma unroll
    for (int nt = 0; nt < 2; nt++) {
        int col = n0 + wn + nt * 16 + lm;
        float bvv = bias[col];
        #pragma unroll
        for (int mt = 0; mt < 2; mt++) {
            #pragma unroll
            for (int r = 0; r < 4; r++) {
                int row = m0 + wm + mt * 16 + quad * 4 + r;
                outp[(size_t)row * Cv + col] = acc[mt][nt][r] + bvv;
            }
        }
    }
}

// ---------------- flash attention (R6 structure + lP XOR-swizzle) ----------------
// 512 blocks x 512 thr. Block = (bh, qt): 128 q-rows. 8 waves = 2 groups of 4;
// group g handles 64-key tiles kt = 2i+g. Fixed-exponent softmax.
// lP now uses the SAME row-XOR swizzle as lK/lVT (col ^= (lm&7)<<3, stride 64):
// pf read start-bank = 4*((4ks+quad)^(lm&7)) -> 8 distinct 4-bank windows,
// 2 lanes each = conflict-free (was ~8-way at stride 72). lP = 32 KB; the f32
// merge buffer exactly fills lP, so lL overlays the then-dead lK.
__global__ __launch_bounds__(512) void attn(
    const u16* __restrict__ Qp, const u16* __restrict__ Kp,
    const u16* __restrict__ VTg, u16* __restrict__ Op)
{
    __shared__ u16 lK[2][64 * 64];    // per-group K-tile [key][d], cols XOR-swizzled
    __shared__ u16 lVT[2][64 * 64];   // per-group V^T tile [d][key], cols XOR-swizzled
    __shared__ u16 lP[8][32][64];     // per-wave P, cols XOR-swizzled by (lm&7)

    const int tid  = threadIdx.x;
    const int lane = tid & 63, w = tid >> 6;     // w 0..7
    const int g = w >> 2, wl = w & 3;            // group, wave-in-group
    const int quad = lane >> 4, lm = lane & 15;

    const int idx  = blockIdx.x;
    const int half = idx >> 8;
    const int grp  = idx & 255;
    const int bh   = (half << 4) | (grp >> 4);   // pairs (idx, idx+256): diff bh, compl. qt
    const int j    = grp & 15;
    const int qt   = half ? j : 15 - j;
    const int h = bh & 15, b = bh >> 4;

    const int qb = qt * 128;
    const size_t headoff = (size_t)b * Tv * Cv + (size_t)h * Dv;
    const size_t vthead  = (size_t)h * 64 * Mv + (size_t)b * Tv;

    // Q frags (both groups load the same rows: wl*32 .. wl*32+32)
    bf16x8 qf[2][2];
    #pragma unroll
    for (int nt = 0; nt < 2; nt++) {
        const u16* qptr = Qp + headoff + (size_t)(qb + wl * 32 + nt * 16 + lm) * Cv + quad * 8;
        qf[0][nt] = *(const bf16x8*)(qptr);
        qf[1][nt] = *(const bf16x8*)(qptr + 32);
    }

    f32x4 zero = {0.f, 0.f, 0.f, 0.f};
    f32x4 oacc[2][4];
    #pragma unroll
    for (int mt = 0; mt < 2; mt++)
        #pragma unroll
        for (int nt = 0; nt < 4; nt++) oacc[mt][nt] = zero;
    float Lp[2] = {0.f, 0.f};

    const float SC = 0.18033688011112042f;  // (1/sqrt(64)) * log2(e)
    const int rowi = lane >> 3, seg = lane & 7;
    const int pswz = (lm & 7) << 3;         // lP column XOR key (8-u16 granular)

    auto stage = [&](int kt) {
        const int k0 = kt * 64;
        #pragma unroll
        for (int hf = 0; hf < 2; hf++) {
            int rbase = wl * 16 + hf * 8;
            int row = rbase + rowi;
            int gseg = seg ^ (row & 7);
            gl_lds16(Kp + headoff + (size_t)(k0 + row) * Cv + gseg * 8, &lK[g][rbase * 64]);
            gl_lds16(VTg + vthead + (size_t)row * Mv + k0 + gseg * 8, &lVT[g][rbase * 64]);
        }
    };

    auto body = [&](int kt, bool domask) __attribute__((always_inline)) {
        const int k0 = kt * 64;
        // S^T = K Q^T
        f32x4 stt[4][2];
        #pragma unroll
        for (int mt = 0; mt < 4; mt++)
            #pragma unroll
            for (int nt = 0; nt < 2; nt++) stt[mt][nt] = zero;
        __builtin_amdgcn_s_setprio(1);
        #pragma unroll
        for (int ks = 0; ks < 2; ks++) {
            #pragma unroll
            for (int mt = 0; mt < 4; mt++) {
                bf16x8 kf = *(const bf16x8*)
                    &lK[g][(mt * 16 + lm) * 64 + (((ks * 4 + quad) ^ (lm & 7)) * 8)];
                #pragma unroll
                for (int nt = 0; nt < 2; nt++)
                    stt[mt][nt] = MFMA16(kf, qf[ks][nt], stt[mt][nt]);
            }
        }
        __builtin_amdgcn_s_setprio(0);
        // softmax (fixed exponent), pack to lP (col XOR-swizzled by row&7 = lm&7)
        #pragma unroll
        for (int mt = 0; mt < 4; mt++) {
            #pragma unroll
            for (int nt = 0; nt < 2; nt++) {
                const int keyb = k0 + mt * 16 + quad * 4;
                const int qrow = qb + wl * 32 + nt * 16 + lm;
                float e0 = __builtin_amdgcn_exp2f(fmaf(stt[mt][nt][0], SC, -16.f));
                float e1 = __builtin_amdgcn_exp2f(fmaf(stt[mt][nt][1], SC, -16.f));
                float e2 = __builtin_amdgcn_exp2f(fmaf(stt[mt][nt][2], SC, -16.f));
                float e3 = __builtin_amdgcn_exp2f(fmaf(stt[mt][nt][3], SC, -16.f));
                if (domask) {
                    if (keyb + 0 > qrow) e0 = 0.f;
                    if (keyb + 1 > qrow) e1 = 0.f;
                    if (keyb + 2 > qrow) e2 = 0.f;
                    if (keyb + 3 > qrow) e3 = 0.f;
                }
                Lp[nt] += e0 + e1 + e2 + e3;
                ushort4 pk;
                pk.x = (u16)(__float_as_uint(e0) >> 16);
                pk.y = (u16)(__float_as_uint(e1) >> 16);
                pk.z = (u16)(__float_as_uint(e2) >> 16);
                pk.w = (u16)(__float_as_uint(e3) >> 16);
                *(ushort4*)&lP[w][nt * 16 + lm][(mt * 16 + quad * 4) ^ pswz] = pk;
            }
        }
        // O += P V
        __builtin_amdgcn_s_setprio(1);
        #pragma unroll
        for (int ks = 0; ks < 2; ks++) {
            bf16x8 pf[2];
            #pragma unroll
            for (int mt = 0; mt < 2; mt++)
                pf[mt] = *(const bf16x8*)&lP[w][mt * 16 + lm][(ks * 32 + quad * 8) ^ pswz];
            #pragma unroll
            for (int nt = 0; nt < 4; nt++) {
                bf16x8 vf = *(const bf16x8*)
                    &lVT[g][(nt * 16 + lm) * 64 + (((ks * 4 + quad) ^ (lm & 7)) * 8)];
                #pragma unroll
                for (int mt = 0; mt < 2; mt++)
                    oacc[mt][nt] = MFMA16(pf[mt], vf, oacc[mt][nt]);
            }
        }
        __builtin_amdgcn_s_setprio(0);
    };

    // main loop: group g's tile i is kt = 2i+g; last iter (i==qt) needs masking
    for (int i = 0; i < qt; i++) {
        if (i) __syncthreads();        // prior compute done before overwrite
        stage(2 * i + g);
        __syncthreads();               // staging visible
        body(2 * i + g, false);
    }
    if (qt) __syncthreads();
    stage(2 * qt + g);
    __syncthreads();
    body(2 * qt + g, true);
    __syncthreads();                   // lP/lK reads done before merge reuses them

    // ---- merge group partials through LDS (lO overlays lP; lL overlays lK) ----
    float* lO = (float*)&lP[0][0][0];            // [32 slots][256 lanes] = 32 KB exact
    float* lL = (float*)&lK[0][0];               // [2][256] in dead K buffer
    const int t = tid & 255;
    if (g == 1) {
        #pragma unroll
        for (int mt = 0; mt < 2; mt++)
            #pragma unroll
            for (int nt = 0; nt < 4; nt++)
                #pragma unroll
                for (int r = 0; r < 4; r++)
                    lO[(mt * 16 + nt * 4 + r) * 256 + t] = oacc[mt][nt][r];
        lL[t] = Lp[0];
        lL[256 + t] = Lp[1];
    }
    __syncthreads();
    if (g == 0) {
        #pragma unroll
        for (int mt = 0; mt < 2; mt++)
            #pragma unroll
            for (int nt = 0; nt < 4; nt++)
                #pragma unroll
                for (int r = 0; r < 4; r++)
                    oacc[mt][nt][r] += lO[(mt * 16 + nt * 4 + r) * 256 + t];
        Lp[0] += lL[t];
        Lp[1] += lL[256 + t];

        float Lred[2];
        #pragma unroll
        for (int nt = 0; nt < 2; nt++) {
            float L = Lp[nt];
            L += __shfl_xor(L, 16, 64);
            L += __shfl_xor(L, 32, 64);
            Lred[nt] = 1.0f / L;
        }
        #pragma unroll
        for (int mt = 0; mt < 2; mt++) {
            float inv[4];
            #pragma unroll
            for (int r = 0; r < 4; r++)
                inv[r] = __shfl(Lred[mt], (lane & 48) | (quad * 4 + r), 64);
            #pragma unroll
            for (int nt = 0; nt < 4; nt++) {
                #pragma unroll
                for (int r = 0; r < 4; r++) {
                    int row = qb + wl * 32 + mt * 16 + quad * 4 + r;
                    Op[headoff + (size_t)row * Cv + nt * 16 + lm] = f2bf(oacc[mt][nt][r] * inv[r]);
                }
            }
        }
    }
}

// ---------------- launcher ----------------
extern "C" void kernel_launch(void* const* d_in, const int* in_sizes, int n_in,
                              void* d_out, int out_size, void* d_ws, size_t ws_size,
                              hipStream_t stream) {
    const float* x  = (const float*)d_in[0];
    const float* Wq = (const float*)d_in[1];
    const float* bq = (const float*)d_in[2];
    const float* Wk = (const float*)d_in[3];
    const float* bk = (const float*)d_in[4];
    const float* Wv = (const float*)d_in[5];
    const float* bv = (const float*)d_in[6];
    const float* Wo = (const float*)d_in[7];
    const float* bo = (const float*)d_in[8];
    u16* ws = (u16*)d_ws;

    convert_all<<<8192, 256, 0, stream>>>(x, Wq, Wk, Wv, Wo, ws);

    gemm_qkv<<<768, 256, 0, stream>>>(
        ws + OFF_XB, ws + OFF_WQ, ws + OFF_WK, ws + OFF_WV,
        bq, bk, bv, ws + OFF_Q, ws + OFF_K, ws + OFF_VT);

    attn<<<512, 512, 0, stream>>>(ws + OFF_Q, ws + OFF_K, ws + OFF_VT, ws + OFF_A);

    gemm_o64<<<512, 512, 0, stream>>>(ws + OFF_A, ws + OFF_WO, bo, (float*)d_out);
}

// Round 13
// 171.296 us; speedup vs baseline: 1.0871x; 1.0871x over previous
//
#include <hip/hip_runtime.h>

typedef unsigned short u16;
typedef __attribute__((ext_vector_type(8))) __bf16 bf16x8;
typedef __attribute__((ext_vector_type(4))) float f32x4;
typedef __attribute__((ext_vector_type(4))) unsigned int u32x4;

#define MFMA16(a, b, c) __builtin_amdgcn_mfma_f32_16x16x32_bf16(a, b, c, 0, 0, 0)

__device__ __forceinline__ u16 f2bf(float f) {
    unsigned u = __float_as_uint(f);
    u = (u + 0x7FFFu + ((u >> 16) & 1u)) >> 16;
    return (u16)u;
}

// async global->LDS, 16B per lane; LDS dest = wave-uniform base + lane*16
__device__ __forceinline__ void gl_lds16(const u16* g, u16* l) {
    __builtin_amdgcn_global_load_lds(
        (const __attribute__((address_space(1))) unsigned int*)g,
        (__attribute__((address_space(3))) unsigned int*)l, 16, 0, 0);
}

static constexpr int Bv = 2, Tv = 2048, Cv = 1024, Hv = 16, Dv = 64;
static constexpr int Mv = Bv * Tv; // 4096

// ws element offsets (u16 elements)
static constexpr size_t OFF_XB = 0;                      // x bf16       [4096,1024]
static constexpr size_t OFF_WQ = 4194304;                // Wq bf16      [1024,1024]
static constexpr size_t OFF_WK = OFF_WQ + 1048576;
static constexpr size_t OFF_WV = OFF_WK + 1048576;
static constexpr size_t OFF_WO = OFF_WV + 1048576;
static constexpr size_t OFF_Q  = OFF_WO + 1048576;       // Q bf16 [M, C]
static constexpr size_t OFF_K  = OFF_Q + 4194304;        // K bf16 [M, C]
static constexpr size_t OFF_VT = OFF_K + 4194304;        // V^T bf16 [C, M]
static constexpr size_t OFF_A  = OFF_VT + 4194304;       // attended bf16 [M, C]

// ---------------- fp32 -> bf16 convert (x + 4 weights) ----------------
__global__ __launch_bounds__(256) void convert_all(
    const float* __restrict__ x,
    const float* __restrict__ wq, const float* __restrict__ wk,
    const float* __restrict__ wv, const float* __restrict__ wo,
    u16* __restrict__ dst)
{
    int i4 = blockIdx.x * blockDim.x + threadIdx.x;
    if (i4 >= 2097152) return;
    int idx = i4 * 4;
    const float* src; int off;
    if (idx < 4194304) { src = x; off = idx; }
    else {
        int rel = idx - 4194304;
        int j = rel >> 20;
        off = rel & 1048575;
        src = (j == 0) ? wq : (j == 1) ? wk : (j == 2) ? wv : wo;
    }
    float4 v = *(const float4*)(src + off);
    ushort4 o;
    o.x = f2bf(v.x); o.y = f2bf(v.y); o.z = f2bf(v.z); o.w = f2bf(v.w);
    *(ushort4*)(dst + idx) = o;
}

// ---------------- 128x128-tile bf16 GEMM, BK=32, packed LDS (qkv) ----------------
// Best-measured qkv structure (R5). 4 waves, 64x64 sub-tiles, packed [64][64]
// LDS, 32 KB double buffer, counted-vmcnt pipeline.
template <bool OUT_BF16, bool ROWBIAS>
__device__ __forceinline__ void gemm128_b32(
    u16* __restrict__ lA0, u16* __restrict__ lB0,
    u16* __restrict__ lA1, u16* __restrict__ lB1,
    const u16* __restrict__ A, const u16* __restrict__ Wt,
    const float* __restrict__ bias, void* __restrict__ outp,
    int m0, int n0, int N, int K)
{
    const int tid  = threadIdx.x;
    const int lane = tid & 63, w = tid >> 6;          // 4 waves
    const int quad = lane >> 4, lm = lane & 15;
    const int wm = (w & 1) * 64, wn = (w >> 1) * 64;  // 2x2 wave grid, 64x64 each
    const int h4A = (w & 1) * 4, h4B = ((w >> 1) & 1) * 4;
    const int rowi = lane >> 3, seg = lane & 7;
    const int raw = seg ^ rowi;
    const int hh  = raw >> 2, qq = raw & 3;

    f32x4 zero = {0.f, 0.f, 0.f, 0.f};
    f32x4 acc[4][4];
    #pragma unroll
    for (int mt = 0; mt < 4; mt++)
        #pragma unroll
        for (int nt = 0; nt < 4; nt++) acc[mt][nt] = zero;

    auto stage = [&](u16* dA, u16* dB, int k0) __attribute__((always_inline)) {
        #pragma unroll
        for (int j = 0; j < 2; j++) {
            int pr0 = w * 16 + j * 8;
            int gr  = pr0 + rowi + (hh << 6);
            gl_lds16(A  + (size_t)(m0 + gr) * K + k0 + qq * 8, &dA[pr0 * 64]);
            gl_lds16(Wt + (size_t)(n0 + gr) * K + k0 + qq * 8, &dB[pr0 * 64]);
        }
    };
    auto compute = [&](const u16* sA, const u16* sB) __attribute__((always_inline)) {
        bf16x8 af[4], bf[4];
        #pragma unroll
        for (int mt = 0; mt < 4; mt++)
            af[mt] = *(const bf16x8*)&sA[(mt * 16 + lm) * 64 + (((h4A + quad) ^ (lm & 7)) * 8)];
        #pragma unroll
        for (int nt = 0; nt < 4; nt++)
            bf[nt] = *(const bf16x8*)&sB[(nt * 16 + lm) * 64 + (((h4B + quad) ^ (lm & 7)) * 8)];
        #pragma unroll
        for (int mt = 0; mt < 4; mt++)
            #pragma unroll
            for (int nt = 0; nt < 4; nt++)
                acc[mt][nt] = MFMA16(af[mt], bf[nt], acc[mt][nt]);
    };

    const int NT = K >> 5;               // 32 steps of BK=32
    stage(lA0, lB0, 0);
    stage(lA1, lB1, 32);
    for (int t = 0; t < NT; ++t) {
        if (t + 1 < NT) asm volatile("s_waitcnt vmcnt(4)" ::: "memory");
        else            asm volatile("s_waitcnt vmcnt(0)" ::: "memory");
        __builtin_amdgcn_s_barrier();
        const u16* sA = (t & 1) ? lA1 : lA0;
        const u16* sB = (t & 1) ? lB1 : lB0;
        compute(sA, sB);
        asm volatile("s_waitcnt lgkmcnt(0)" ::: "memory");
        __builtin_amdgcn_s_barrier();
        if (t + 2 < NT) stage((t & 1) ? lA1 : lA0, (t & 1) ? lB1 : lB0, (t + 2) << 5);
    }

    #pragma unroll
    for (int nt = 0; nt < 4; nt++) {
        int col = n0 + wn + nt * 16 + lm;
        float cb = ROWBIAS ? 0.f : bias[col];
        #pragma unroll
        for (int mt = 0; mt < 4; mt++) {
            #pragma unroll
            for (int r = 0; r < 4; r++) {
                int row = m0 + wm + mt * 16 + quad * 4 + r;
                float v = acc[mt][nt][r] + (ROWBIAS ? bias[row] : cb);
                if (OUT_BF16) ((u16*)outp)[(size_t)row * N + col] = f2bf(v);
                else          ((float*)outp)[(size_t)row * N + col] = v;
            }
        }
    }
}

// fused QKV: 1-D grid of 768 blocks x 256 threads, XCD-swizzled
__global__ __launch_bounds__(256, 3) void gemm_qkv(
    const u16* __restrict__ A,
    const u16* __restrict__ Wq, const u16* __restrict__ Wk, const u16* __restrict__ Wv,
    const float* __restrict__ bq, const float* __restrict__ bk, const float* __restrict__ bv,
    u16* __restrict__ Q, u16* __restrict__ K, u16* __restrict__ VT)
{
    __shared__ u16 lA0[64 * 64];   // packed [64 phys rows][64 cols] = 8 KB each
    __shared__ u16 lB0[64 * 64];
    __shared__ u16 lA1[64 * 64];
    __shared__ u16 lB1[64 * 64];

    int bid = blockIdx.x;
    int sw  = (bid & 7) * 96 + (bid >> 3);
    int g2  = sw >> 5;          // 0..23 = which*8 + col
    int row = sw & 31;          // 0..31 row tile
    int which = g2 >> 3, col = g2 & 7;

    if (which == 0) {
        gemm128_b32<true, false>(lA0, lB0, lA1, lB1, A, Wq, bq, Q, row * 128, col * 128, Cv, Cv);
    } else if (which == 1) {
        gemm128_b32<true, false>(lA0, lB0, lA1, lB1, A, Wk, bk, K, row * 128, col * 128, Cv, Cv);
    } else {
        gemm128_b32<true, true>(lA0, lB0, lA1, lB1, Wv, A, bv, VT, col * 128, row * 128, Mv, Cv);
    }
}

// output proj (R4 version, best measured): 128x64 tiles, BK=64, 512 threads
// (8 waves, 32x32 each), counted-vmcnt dbuf pipeline, 1-D grid 512 blocks.
__global__ __launch_bounds__(512) void gemm_o64(
    const u16* __restrict__ A, const u16* __restrict__ Wt,
    const float* __restrict__ bias, float* __restrict__ outp)
{
    __shared__ u16 lA0[128 * 64];
    __shared__ u16 lA1[128 * 64];
    __shared__ u16 lB0[64 * 64];
    __shared__ u16 lB1[64 * 64];

    const int tid  = threadIdx.x;
    const int lane = tid & 63, w = tid >> 6;          // 0..7
    const int quad = lane >> 4, lm = lane & 15;
    const int wm = (w & 3) * 32, wn = (w >> 2) * 32;  // 4x2 wave grid, 32x32 each

    int bid = blockIdx.x;                  // 512 % 8 == 0
    int sw  = (bid & 7) * 64 + (bid >> 3);
    const int n0 = (sw >> 5) * 64;         // col tile 0..15
    const int m0 = (sw & 31) * 128;        // row tile 0..31
    const int K = Cv;
    const int rowi = lane >> 3, seg = lane & 7;

    f32x4 zero = {0.f, 0.f, 0.f, 0.f};
    f32x4 acc[2][2];
    #pragma unroll
    for (int mt = 0; mt < 2; mt++)
        #pragma unroll
        for (int nt = 0; nt < 2; nt++) acc[mt][nt] = zero;

    auto stage = [&](u16* dA, u16* dB, int k0) __attribute__((always_inline)) {
        #pragma unroll
        for (int i = 0; i < 2; i++) {
            int rbase = w * 16 + i * 8;
            int row = rbase + rowi;
            int gseg = seg ^ (row & 7);
            gl_lds16(A + (size_t)(m0 + row) * K + k0 + gseg * 8, &dA[rbase * 64]);
        }
        {
            int rbase = w * 8, row = rbase + rowi;     // 8 waves x 8 rows = 64
            gl_lds16(Wt + (size_t)(n0 + row) * K + k0 + ((seg ^ (row & 7))) * 8, &dB[rbase * 64]);
        }
    };
    auto compute = [&](const u16* sA, const u16* sB) __attribute__((always_inline)) {
        #pragma unroll
        for (int ks = 0; ks < 2; ks++) {
            const int swz = ((ks * 4 + quad) ^ (lm & 7)) * 8;
            bf16x8 af[2], bf[2];
            #pragma unroll
            for (int mt = 0; mt < 2; mt++)
                af[mt] = *(const bf16x8*)&sA[(wm + mt * 16 + lm) * 64 + swz];
            #pragma unroll
            for (int nt = 0; nt < 2; nt++)
                bf[nt] = *(const bf16x8*)&sB[(wn + nt * 16 + lm) * 64 + swz];
            #pragma unroll
            for (int mt = 0; mt < 2; mt++)
                #pragma unroll
                for (int nt = 0; nt < 2; nt++)
                    acc[mt][nt] = MFMA16(af[mt], bf[nt], acc[mt][nt]);
        }
    };

    const int NT = K >> 6;                 // 16
    stage(lA0, lB0, 0);
    stage(lA1, lB1, 64);
    for (int t = 0; t < NT; ++t) {
        if (t + 1 < NT) asm volatile("s_waitcnt vmcnt(3)" ::: "memory");
        else            asm volatile("s_waitcnt vmcnt(0)" ::: "memory");
        __builtin_amdgcn_s_barrier();
        u16* sA = (t & 1) ? lA1 : lA0;
        u16* sB = (t & 1) ? lB1 : lB0;
        compute(sA, sB);
        asm volatile("s_waitcnt lgkmcnt(0)" ::: "memory");
        __builtin_amdgcn_s_barrier();
        if (t + 2 < NT) stage(sA, sB, (t + 2) << 6);
    }

    #pragma unroll
    for (int nt = 0; nt < 2; nt++) {
        int col = n0 + wn + nt * 16 + lm;
        float bvv = bias[col];
        #pragma unroll
        for (int mt = 0; mt < 2; mt++) {
            #pragma unroll
            for (int r = 0; r < 4; r++) {
                int row = m0 + wm + mt * 16 + quad * 4 + r;
                outp[(size_t)row * Cv + col] = acc[mt][nt][r] + bvv;
            }
        }
    }
}

// ---------------- flash attention (R6/R11 version, best measured) ----------------
// 512 blocks x 512 thr. Block = (bh, qt): 128 q-rows. 8 waves = 2 groups of 4;
// group g handles 64-key tiles kt = 2i+g, i in [0, qt+1) -- exactly even split.
// Fixed-exponent softmax => partial (O, L) over disjoint keys simply ADD.
// T5 setprio around MFMA clusters. lP stride 72: odd stride spreads the pack
// writes conflict-free (R12 showed stride-64+XOR trades write conflicts for
// read conflicts at a net loss).
__global__ __launch_bounds__(512) void attn(
    const u16* __restrict__ Qp, const u16* __restrict__ Kp,
    const u16* __restrict__ VTg, u16* __restrict__ Op)
{
    __shared__ u16 lK[2][64 * 64];    // per-group K-tile [key][d], cols XOR-swizzled
    __shared__ u16 lVT[2][64 * 64];   // per-group V^T tile [d][key], cols XOR-swizzled
    __shared__ u16 lP[8][32][72];     // per-wave P; reused as f32 merge buffer after loop

    const int tid  = threadIdx.x;
    const int lane = tid & 63, w = tid >> 6;     // w 0..7
    const int g = w >> 2, wl = w & 3;            // group, wave-in-group
    const int quad = lane >> 4, lm = lane & 15;

    const int idx  = blockIdx.x;
    const int half = idx >> 8;
    const int grp  = idx & 255;
    const int bh   = (half << 4) | (grp >> 4);   // pairs (idx, idx+256): diff bh, compl. qt
    const int j    = grp & 15;
    const int qt   = half ? j : 15 - j;
    const int h = bh & 15, b = bh >> 4;

    const int qb = qt * 128;
    const size_t headoff = (size_t)b * Tv * Cv + (size_t)h * Dv;
    const size_t vthead  = (size_t)h * 64 * Mv + (size_t)b * Tv;

    // Q frags (both groups load the same rows: wl*32 .. wl*32+32)
    bf16x8 qf[2][2];
    #pragma unroll
    for (int nt = 0; nt < 2; nt++) {
        const u16* qptr = Qp + headoff + (size_t)(qb + wl * 32 + nt * 16 + lm) * Cv + quad * 8;
        qf[0][nt] = *(const bf16x8*)(qptr);
        qf[1][nt] = *(const bf16x8*)(qptr + 32);
    }

    f32x4 zero = {0.f, 0.f, 0.f, 0.f};
    f32x4 oacc[2][4];
    #pragma unroll
    for (int mt = 0; mt < 2; mt++)
        #pragma unroll
        for (int nt = 0; nt < 4; nt++) oacc[mt][nt] = zero;
    float Lp[2] = {0.f, 0.f};

    const float SC = 0.18033688011112042f;  // (1/sqrt(64)) * log2(e)
    const int rowi = lane >> 3, seg = lane & 7;

    auto stage = [&](int kt) {
        const int k0 = kt * 64;
        #pragma unroll
        for (int hf = 0; hf < 2; hf++) {
            int rbase = wl * 16 + hf * 8;
            int row = rbase + rowi;
            int gseg = seg ^ (row & 7);
            gl_lds16(Kp + headoff + (size_t)(k0 + row) * Cv + gseg * 8, &lK[g][rbase * 64]);
            gl_lds16(VTg + vthead + (size_t)row * Mv + k0 + gseg * 8, &lVT[g][rbase * 64]);
        }
    };

    auto body = [&](int kt, bool domask) __attribute__((always_inline)) {
        const int k0 = kt * 64;
        // S^T = K Q^T
        f32x4 stt[4][2];
        #pragma unroll
        for (int mt = 0; mt < 4; mt++)
            #pragma unroll
            for (int nt = 0; nt < 2; nt++) stt[mt][nt] = zero;
        __builtin_amdgcn_s_setprio(1);
        #pragma unroll
        for (int ks = 0; ks < 2; ks++) {
            #pragma unroll
            for (int mt = 0; mt < 4; mt++) {
                bf16x8 kf = *(const bf16x8*)
                    &lK[g][(mt * 16 + lm) * 64 + (((ks * 4 + quad) ^ (lm & 7)) * 8)];
                #pragma unroll
                for (int nt = 0; nt < 2; nt++)
                    stt[mt][nt] = MFMA16(kf, qf[ks][nt], stt[mt][nt]);
            }
        }
        __builtin_amdgcn_s_setprio(0);
        // softmax (fixed exponent), pack to lP
        #pragma unroll
        for (int mt = 0; mt < 4; mt++) {
            #pragma unroll
            for (int nt = 0; nt < 2; nt++) {
                const int keyb = k0 + mt * 16 + quad * 4;
                const int qrow = qb + wl * 32 + nt * 16 + lm;
                float e0 = __builtin_amdgcn_exp2f(fmaf(stt[mt][nt][0], SC, -16.f));
                float e1 = __builtin_amdgcn_exp2f(fmaf(stt[mt][nt][1], SC, -16.f));
                float e2 = __builtin_amdgcn_exp2f(fmaf(stt[mt][nt][2], SC, -16.f));
                float e3 = __builtin_amdgcn_exp2f(fmaf(stt[mt][nt][3], SC, -16.f));
                if (domask) {
                    if (keyb + 0 > qrow) e0 = 0.f;
                    if (keyb + 1 > qrow) e1 = 0.f;
                    if (keyb + 2 > qrow) e2 = 0.f;
                    if (keyb + 3 > qrow) e3 = 0.f;
                }
                Lp[nt] += e0 + e1 + e2 + e3;
                ushort4 pk;
                pk.x = (u16)(__float_as_uint(e0) >> 16);
                pk.y = (u16)(__float_as_uint(e1) >> 16);
                pk.z = (u16)(__float_as_uint(e2) >> 16);
                pk.w = (u16)(__float_as_uint(e3) >> 16);
                *(ushort4*)&lP[w][nt * 16 + lm][mt * 16 + quad * 4] = pk;
            }
        }
        // O += P V
        __builtin_amdgcn_s_setprio(1);
        #pragma unroll
        for (int ks = 0; ks < 2; ks++) {
            bf16x8 pf[2];
            #pragma unroll
            for (int mt = 0; mt < 2; mt++)
                pf[mt] = *(const bf16x8*)&lP[w][mt * 16 + lm][ks * 32 + quad * 8];
            #pragma unroll
            for (int nt = 0; nt < 4; nt++) {
                bf16x8 vf = *(const bf16x8*)
                    &lVT[g][(nt * 16 + lm) * 64 + (((ks * 4 + quad) ^ (lm & 7)) * 8)];
                #pragma unroll
                for (int mt = 0; mt < 2; mt++)
                    oacc[mt][nt] = MFMA16(pf[mt], vf, oacc[mt][nt]);
            }
        }
        __builtin_amdgcn_s_setprio(0);
    };

    // main loop: group g's tile i is kt = 2i+g; last iter (i==qt) needs masking
    for (int i = 0; i < qt; i++) {
        if (i) __syncthreads();        // prior compute done before overwrite
        stage(2 * i + g);
        __syncthreads();               // staging visible
        body(2 * i + g, false);
    }
    if (qt) __syncthreads();
    stage(2 * qt + g);
    __syncthreads();
    body(2 * qt + g, true);
    __syncthreads();                   // lP reads done before merge reuses it

    // ---- merge group partials through LDS (reuse lP as f32 buffer) ----
    float* lO = (float*)&lP[0][0][0];            // [32 slots][256 lanes]
    float* lL = lO + 32 * 256;                   // [2][256]
    const int t = tid & 255;
    if (g == 1) {
        #pragma unroll
        for (int mt = 0; mt < 2; mt++)
            #pragma unroll
            for (int nt = 0; nt < 4; nt++)
                #pragma unroll
                for (int r = 0; r < 4; r++)
                    lO[(mt * 16 + nt * 4 + r) * 256 + t] = oacc[mt][nt][r];
        lL[t] = Lp[0];
        lL[256 + t] = Lp[1];
    }
    __syncthreads();
    if (g == 0) {
        #pragma unroll
        for (int mt = 0; mt < 2; mt++)
            #pragma unroll
            for (int nt = 0; nt < 4; nt++)
                #pragma unroll
                for (int r = 0; r < 4; r++)
                    oacc[mt][nt][r] += lO[(mt * 16 + nt * 4 + r) * 256 + t];
        Lp[0] += lL[t];
        Lp[1] += lL[256 + t];

        float Lred[2];
        #pragma unroll
        for (int nt = 0; nt < 2; nt++) {
            float L = Lp[nt];
            L += __shfl_xor(L, 16, 64);
            L += __shfl_xor(L, 32, 64);
            Lred[nt] = 1.0f / L;
        }
        #pragma unroll
        for (int mt = 0; mt < 2; mt++) {
            float inv[4];
            #pragma unroll
            for (int r = 0; r < 4; r++)
                inv[r] = __shfl(Lred[mt], (lane & 48) | (quad * 4 + r), 64);
            #pragma unroll
            for (int nt = 0; nt < 4; nt++) {
                #pragma unroll
                for (int r = 0; r < 4; r++) {
                    int row = qb + wl * 32 + mt * 16 + quad * 4 + r;
                    Op[headoff + (size_t)row * Cv + nt * 16 + lm] = f2bf(oacc[mt][nt][r] * inv[r]);
                }
            }
        }
    }
}

// ---------------- launcher ----------------
extern "C" void kernel_launch(void* const* d_in, const int* in_sizes, int n_in,
                              void* d_out, int out_size, void* d_ws, size_t ws_size,
                              hipStream_t stream) {
    const float* x  = (const float*)d_in[0];
    const float* Wq = (const float*)d_in[1];
    const float* bq = (const float*)d_in[2];
    const float* Wk = (const float*)d_in[3];
    const float* bk = (const float*)d_in[4];
    const float* Wv = (const float*)d_in[5];
    const float* bv = (const float*)d_in[6];
    const float* Wo = (const float*)d_in[7];
    const float* bo = (const float*)d_in[8];
    u16* ws = (u16*)d_ws;

    convert_all<<<8192, 256, 0, stream>>>(x, Wq, Wk, Wv, Wo, ws);

    gemm_qkv<<<768, 256, 0, stream>>>(
        ws + OFF_XB, ws + OFF_WQ, ws + OFF_WK, ws + OFF_WV,
        bq, bk, bv, ws + OFF_Q, ws + OFF_K, ws + OFF_VT);

    attn<<<512, 512, 0, stream>>>(ws + OFF_Q, ws + OFF_K, ws + OFF_VT, ws + OFF_A);

    gemm_o64<<<512, 512, 0, stream>>>(ws + OFF_A, ws + OFF_WO, bo, (float*)d_out);
}